// Round 8
// baseline (407.784 us; speedup 1.0000x reference)
//
#include <hip/hip_runtime.h>
#include <math.h>

#define DDIM 16
#define NSTEPS 64
#define LUT_E 256          // entries: top 8 bits of f16 (sign+5exp+2mant)
#define LUT_R 16           // replicas (lane & 15 selects copy) -> 16KB in LDS

typedef __fp16   fp16x2  __attribute__((ext_vector_type(2)));
typedef _Float16 h2      __attribute__((ext_vector_type(2)));
typedef _Float16 half4   __attribute__((ext_vector_type(4)));
typedef float    floatx4 __attribute__((ext_vector_type(4)));

union pk_u      { fp16x2 fv; h2 hv; unsigned u; };
union h2x2_h4   { h2 g2[2]; half4 h4; };
union pk2_to_h4 { fp16x2 p2[2]; half4 h4; };
union us_h      { unsigned short u; _Float16 h; };

// ---------------------------------------------------------------------------
// Pre-pack W^T / V^T into per-lane MFMA A-operand fragments (f16).
// V fragments are pre-scaled by 1/NSTEPS.
// ---------------------------------------------------------------------------
__global__ __launch_bounds__(256) void pack_wv(const float* __restrict__ W,
                                               const float* __restrict__ V,
                                               half4* __restrict__ pw,
                                               half4* __restrict__ pv)
{
    int t = blockIdx.x * 256 + threadIdx.x;   // 0..4095 = 64 steps * 64 lanes
    int L = t & 63;
    int s = t >> 6;
    int q = L >> 4, r = L & 15;
    const float inv_n = 1.0f / (float)NSTEPS;
    const float* Ws = W + s * DDIM * DDIM;
    const float* Vs = V + s * DDIM * DDIM;
    half4 w, v;
    #pragma unroll
    for (int j = 0; j < 4; ++j) {
        w[j] = (_Float16)Ws[(4 * q + j) * DDIM + r];
        v[j] = (_Float16)(Vs[(4 * q + j) * DDIM + r] * inv_n);
    }
    pw[t] = w;
    pv[t] = v;
}

// ---------------------------------------------------------------------------
// 256-entry GELU LUT indexed by the TOP 8 BITS of the f16 pattern
// (sign + 5 exp + 2 mantissa): 4 log-spaced segments per binade over the
// whole f16 domain, no clamping. Entry i: packed f16 (a,b), low16 = a,
// gelu(x) ~= a*x + b on segment [bits(i<<8), bits((i+1)<<8)).
// Worst PWL error ~4e-3; the activation is scaled by 1/64 before entering h,
// so end-to-end impact is ~4e-3 (well below the 0.03125 harness tolerance).
// ---------------------------------------------------------------------------
__global__ __launch_bounds__(256) void build_lut256(unsigned* __restrict__ lut)
{
    int i = threadIdx.x;                      // 0..255, single block
    int sign = i >> 7;
    int eo = (i >> 2) & 31;
    int en = ((i + 1) >> 2) & 31;
    float a, b;
    if (eo == 31 || en == 31) {               // segment touches inf/nan codes
        a = sign ? 0.0f : 1.0f;               // g = x (pos huge) / 0 (neg huge)
        b = 0.0f;
    } else {
        us_h c0, c1;
        c0.u = (unsigned short)(i << 8);
        c1.u = (unsigned short)((i + 1) << 8);
        float x0 = (float)c0.h, x1 = (float)c1.h;
        float g0 = 0.5f * x0 * (1.0f + erff(x0 * 0.70710678f));
        float g1 = 0.5f * x1 * (1.0f + erff(x1 * 0.70710678f));
        a = (g1 - g0) / (x1 - x0);
        b = g0 - a * x0;
    }
    us_h ah, bh;
    ah.h = (_Float16)a;
    bh.h = (_Float16)b;
    lut[i] = ((unsigned)bh.u << 16) | (unsigned)ah.u;
}

// ---------------------------------------------------------------------------
// Main kernel (R4 structure, 4 tiles/wave). GELU gathers hit a 16x-replicated
// LDS LUT: u32 slot = entry*16 + (lane&15)  =>  bank = (entry*16 + r) % 32.
// The 4 lanes sharing r map to <=2 banks; 2-way LDS conflicts are free on
// CDNA4, so gathers are ~conflict-free regardless of index distribution
// (R4-R6 showed 2/3 of LDS-pipe time was random-gather bank conflicts).
// ---------------------------------------------------------------------------
__global__ __launch_bounds__(256) void resnet_mfma_kernel(
    const float* __restrict__ x,
    const half4* __restrict__ pw,
    const half4* __restrict__ pv,
    const unsigned* __restrict__ lut_g,
    float* __restrict__ out)
{
    __shared__ unsigned lutw[LUT_E * LUT_R];   // 16 KB

    const int tid  = threadIdx.x;
    const int lane = tid & 63;
    const int wave = tid >> 6;
    const int q = lane >> 4, r = lane & 15;

    // Stage replicated LUT: thread t broadcasts entry t into its 16 slots
    // (4 x uint4 stores of the same value).
    {
        unsigned v = lut_g[tid];
        uint4 vv = make_uint4(v, v, v, v);
        uint4* dst = reinterpret_cast<uint4*>(lutw);
        dst[4 * tid + 0] = vv;
        dst[4 * tid + 1] = vv;
        dst[4 * tid + 2] = vv;
        dst[4 * tid + 3] = vv;
    }

    const long rowbase = (long)blockIdx.x * 256 + (long)wave * 64;

    floatx4 h[4];
    #pragma unroll
    for (int t = 0; t < 4; ++t) {
        const float4* p = reinterpret_cast<const float4*>(
            x + (rowbase + t * 16 + r) * DDIM + 4 * q);
        float4 v = *p;
        h[t][0] = v.x; h[t][1] = v.y; h[t][2] = v.z; h[t][3] = v.w;
    }

    half4 wf = pw[lane];
    half4 vf = pv[lane];

    __syncthreads();   // LUT ready

    // Per-lane base: copy (lane&15) -> +4*(lane&15) bytes. Offsets add
    // entry*64 on top, so addr = entry*64 + (lane&15)*4.
    const char* lb = reinterpret_cast<const char*>(lutw) + (r << 2);

    for (int s = 0; s < NSTEPS; ++s) {
        int sn = (s + 1) & (NSTEPS - 1);          // last iter wraps to 0 (unused)
        half4 wfn = pw[sn * 64 + lane];
        half4 vfn = pv[sn * 64 + lane];

        #pragma unroll
        for (int t = 0; t < 4; ++t) {
            pk2_to_h4 hc;
            hc.p2[0] = __builtin_amdgcn_cvt_pkrtz(h[t][0], h[t][1]);
            hc.p2[1] = __builtin_amdgcn_cvt_pkrtz(h[t][2], h[t][3]);

            floatx4 zero = {0.f, 0.f, 0.f, 0.f};
            floatx4 u = __builtin_amdgcn_mfma_f32_16x16x16f16(wf, hc.h4, zero, 0, 0, 0);

            // u -> packed f16 (also the PWL input)
            pk_u p01, p23;
            p01.fv = __builtin_amdgcn_cvt_pkrtz(u[0], u[1]);
            p23.fv = __builtin_amdgcn_cvt_pkrtz(u[2], u[3]);

            // byte offset = (f16 bits >> 8) * 64, from the packed words:
            // (bits >> 2) & 0x3FC0
            unsigned off0 = (p01.u >> 2) & 0x3FC0u;
            unsigned off1 = (p01.u >> 18) & 0x3FC0u;
            unsigned off2 = (p23.u >> 2) & 0x3FC0u;
            unsigned off3 = (p23.u >> 18) & 0x3FC0u;

            unsigned e0 = *reinterpret_cast<const unsigned*>(lb + off0);
            unsigned e1 = *reinterpret_cast<const unsigned*>(lb + off1);
            unsigned e2 = *reinterpret_cast<const unsigned*>(lb + off2);
            unsigned e3 = *reinterpret_cast<const unsigned*>(lb + off3);

            // repack (b|a)(b|a) -> (a1|a0), (b1|b0) ; then packed f16 fma
            pk_u a01, b01, a23, b23;
            a01.u = __builtin_amdgcn_perm(e1, e0, 0x05040100u);
            b01.u = __builtin_amdgcn_perm(e1, e0, 0x07060302u);
            a23.u = __builtin_amdgcn_perm(e3, e2, 0x05040100u);
            b23.u = __builtin_amdgcn_perm(e3, e2, 0x07060302u);

            h2x2_h4 gg;
            gg.g2[0] = a01.hv * p01.hv + b01.hv;   // v_pk_fma_f16
            gg.g2[1] = a23.hv * p23.hv + b23.hv;

            // h += gelu(u) @ (V/N)  (residual add folded into MFMA C operand)
            h[t] = __builtin_amdgcn_mfma_f32_16x16x16f16(vf, gg.h4, h[t], 0, 0, 0);
        }

        wf = wfn; vf = vfn;
    }

    #pragma unroll
    for (int t = 0; t < 4; ++t) {
        float4 v = make_float4(h[t][0], h[t][1], h[t][2], h[t][3]);
        *reinterpret_cast<float4*>(out + (rowbase + t * 16 + r) * DDIM + 4 * q) = v;
    }
}

extern "C" void kernel_launch(void* const* d_in, const int* in_sizes, int n_in,
                              void* d_out, int out_size, void* d_ws, size_t ws_size,
                              hipStream_t stream) {
    const float* x = (const float*)d_in[0];   // [B, 16] fp32
    const float* W = (const float*)d_in[1];   // [64, 16, 16] fp32
    const float* V = (const float*)d_in[2];   // [64, 16, 16] fp32
    float* out = (float*)d_out;

    half4* pw = (half4*)d_ws;                 // 64 steps * 64 lanes * 8B = 32KB
    half4* pv = pw + NSTEPS * 64;             // +32KB
    unsigned* lut = (unsigned*)(pv + NSTEPS * 64); // +1KB (ws_size >= 65KB)

    pack_wv<<<16, 256, 0, stream>>>(W, V, pw, pv);
    build_lut256<<<1, 256, 0, stream>>>(lut);

    int batch = in_sizes[0] / DDIM;           // 2^21
    resnet_mfma_kernel<<<batch / 256, 256, 0, stream>>>(x, pw, pv, lut, out);
}

// Round 9
// 407.763 us; speedup vs baseline: 1.0001x; 1.0001x over previous
//
#include <hip/hip_runtime.h>
#include <math.h>

#define DDIM 16
#define NSTEPS 64
#define LUT_E 256          // entries: top 8 bits of f16 (sign+5exp+2mant)
#define LUT_R 16           // replicas (lane & 15 selects copy) -> 16KB in LDS

typedef __fp16   fp16x2  __attribute__((ext_vector_type(2)));
typedef _Float16 h2      __attribute__((ext_vector_type(2)));
typedef _Float16 half4   __attribute__((ext_vector_type(4)));
typedef float    floatx4 __attribute__((ext_vector_type(4)));

union pk_u      { fp16x2 fv; h2 hv; unsigned u; };
union h2x2_h4   { h2 g2[2]; half4 h4; };
union pk2_to_h4 { fp16x2 p2[2]; half4 h4; };
union us_h      { unsigned short u; _Float16 h; };

// ---------------------------------------------------------------------------
// Pre-pack W^T / V^T into per-lane MFMA A-operand fragments (f16).
// V fragments are pre-scaled by 1/NSTEPS.
// ---------------------------------------------------------------------------
__global__ __launch_bounds__(256) void pack_wv(const float* __restrict__ W,
                                               const float* __restrict__ V,
                                               half4* __restrict__ pw,
                                               half4* __restrict__ pv)
{
    int t = blockIdx.x * 256 + threadIdx.x;   // 0..4095 = 64 steps * 64 lanes
    int L = t & 63;
    int s = t >> 6;
    int q = L >> 4, r = L & 15;
    const float inv_n = 1.0f / (float)NSTEPS;
    const float* Ws = W + s * DDIM * DDIM;
    const float* Vs = V + s * DDIM * DDIM;
    half4 w, v;
    #pragma unroll
    for (int j = 0; j < 4; ++j) {
        w[j] = (_Float16)Ws[(4 * q + j) * DDIM + r];
        v[j] = (_Float16)(Vs[(4 * q + j) * DDIM + r] * inv_n);
    }
    pw[t] = w;
    pv[t] = v;
}

// ---------------------------------------------------------------------------
// 256-entry GELU LUT indexed by the TOP 8 BITS of the f16 pattern (R7).
// Entry i: packed f16 (a,b), low16 = a, gelu(x) ~= a*x + b on the segment.
// ---------------------------------------------------------------------------
__global__ __launch_bounds__(256) void build_lut256(unsigned* __restrict__ lut)
{
    int i = threadIdx.x;                      // 0..255, single block
    int sign = i >> 7;
    int eo = (i >> 2) & 31;
    int en = ((i + 1) >> 2) & 31;
    float a, b;
    if (eo == 31 || en == 31) {               // segment touches inf/nan codes
        a = sign ? 0.0f : 1.0f;
        b = 0.0f;
    } else {
        us_h c0, c1;
        c0.u = (unsigned short)(i << 8);
        c1.u = (unsigned short)((i + 1) << 8);
        float x0 = (float)c0.h, x1 = (float)c1.h;
        float g0 = 0.5f * x0 * (1.0f + erff(x0 * 0.70710678f));
        float g1 = 0.5f * x1 * (1.0f + erff(x1 * 0.70710678f));
        a = (g1 - g0) / (x1 - x0);
        b = g0 - a * x0;
    }
    us_h ah, bh;
    ah.h = (_Float16)a;
    bh.h = (_Float16)b;
    lut[i] = ((unsigned)bh.u << 16) | (unsigned)ah.u;
}

// ---------------------------------------------------------------------------
// Main kernel — TWO-PHASE step structure.
// Phase A (all 4 tiles): cvt h -> MFMA1 -> pkrtz -> offsets -> ISSUE all
//   16 ds_read_b32.  Phase B (all 4 tiles): perm -> pk_fma -> MFMA2.
// This exposes 16 outstanding LDS gathers per wave (vs 4 with the per-tile
// serial pattern R4-R7 compiled to at 32 VGPRs), converting the per-tile
// lgkmcnt(0) drain into counted FIFO waits. LDS latency (~120cy) and MFMA
// latency are then paid ~once per step instead of 4x.
// ---------------------------------------------------------------------------
__global__ __launch_bounds__(256) void resnet_mfma_kernel(
    const float* __restrict__ x,
    const half4* __restrict__ pw,
    const half4* __restrict__ pv,
    const unsigned* __restrict__ lut_g,
    float* __restrict__ out)
{
    __shared__ unsigned lutw[LUT_E * LUT_R];   // 16 KB

    const int tid  = threadIdx.x;
    const int lane = tid & 63;
    const int wave = tid >> 6;
    const int q = lane >> 4, r = lane & 15;

    // Stage replicated LUT: thread t broadcasts entry t into its 16 slots.
    {
        unsigned v = lut_g[tid];
        uint4 vv = make_uint4(v, v, v, v);
        uint4* dst = reinterpret_cast<uint4*>(lutw);
        dst[4 * tid + 0] = vv;
        dst[4 * tid + 1] = vv;
        dst[4 * tid + 2] = vv;
        dst[4 * tid + 3] = vv;
    }

    const long rowbase = (long)blockIdx.x * 256 + (long)wave * 64;

    floatx4 h[4];
    #pragma unroll
    for (int t = 0; t < 4; ++t) {
        const float4* p = reinterpret_cast<const float4*>(
            x + (rowbase + t * 16 + r) * DDIM + 4 * q);
        float4 v = *p;
        h[t][0] = v.x; h[t][1] = v.y; h[t][2] = v.z; h[t][3] = v.w;
    }

    half4 wf = pw[lane];
    half4 vf = pv[lane];

    __syncthreads();   // LUT ready

    // Per-lane base: copy (lane&15) -> +4*(lane&15) bytes; entry adds *64.
    const char* lb = reinterpret_cast<const char*>(lutw) + (r << 2);

    for (int s = 0; s < NSTEPS; ++s) {
        int sn = (s + 1) & (NSTEPS - 1);          // last iter wraps to 0 (unused)
        half4 wfn = pw[sn * 64 + lane];
        half4 vfn = pv[sn * 64 + lane];

        pk_u P01[4], P23[4];
        unsigned e[4][4];

        // ---------------- Phase A: compute u, issue ALL gathers ----------
        #pragma unroll
        for (int t = 0; t < 4; ++t) {
            pk2_to_h4 hc;
            hc.p2[0] = __builtin_amdgcn_cvt_pkrtz(h[t][0], h[t][1]);
            hc.p2[1] = __builtin_amdgcn_cvt_pkrtz(h[t][2], h[t][3]);

            floatx4 zero = {0.f, 0.f, 0.f, 0.f};
            floatx4 u = __builtin_amdgcn_mfma_f32_16x16x16f16(wf, hc.h4, zero, 0, 0, 0);

            P01[t].fv = __builtin_amdgcn_cvt_pkrtz(u[0], u[1]);
            P23[t].fv = __builtin_amdgcn_cvt_pkrtz(u[2], u[3]);

            unsigned off0 = (P01[t].u >> 2) & 0x3FC0u;
            unsigned off1 = (P01[t].u >> 18) & 0x3FC0u;
            unsigned off2 = (P23[t].u >> 2) & 0x3FC0u;
            unsigned off3 = (P23[t].u >> 18) & 0x3FC0u;

            e[t][0] = *reinterpret_cast<const unsigned*>(lb + off0);
            e[t][1] = *reinterpret_cast<const unsigned*>(lb + off1);
            e[t][2] = *reinterpret_cast<const unsigned*>(lb + off2);
            e[t][3] = *reinterpret_cast<const unsigned*>(lb + off3);
        }

        // ---------------- Phase B: consume gathers, second MFMA ----------
        #pragma unroll
        for (int t = 0; t < 4; ++t) {
            pk_u a01, b01, a23, b23;
            a01.u = __builtin_amdgcn_perm(e[t][1], e[t][0], 0x05040100u);
            b01.u = __builtin_amdgcn_perm(e[t][1], e[t][0], 0x07060302u);
            a23.u = __builtin_amdgcn_perm(e[t][3], e[t][2], 0x05040100u);
            b23.u = __builtin_amdgcn_perm(e[t][3], e[t][2], 0x07060302u);

            h2x2_h4 gg;
            gg.g2[0] = a01.hv * P01[t].hv + b01.hv;   // v_pk_fma_f16
            gg.g2[1] = a23.hv * P23[t].hv + b23.hv;

            // h += gelu(u) @ (V/N)  (residual add folded into MFMA C operand)
            h[t] = __builtin_amdgcn_mfma_f32_16x16x16f16(vf, gg.h4, h[t], 0, 0, 0);
        }

        wf = wfn; vf = vfn;
    }

    #pragma unroll
    for (int t = 0; t < 4; ++t) {
        float4 v = make_float4(h[t][0], h[t][1], h[t][2], h[t][3]);
        *reinterpret_cast<float4*>(out + (rowbase + t * 16 + r) * DDIM + 4 * q) = v;
    }
}

extern "C" void kernel_launch(void* const* d_in, const int* in_sizes, int n_in,
                              void* d_out, int out_size, void* d_ws, size_t ws_size,
                              hipStream_t stream) {
    const float* x = (const float*)d_in[0];   // [B, 16] fp32
    const float* W = (const float*)d_in[1];   // [64, 16, 16] fp32
    const float* V = (const float*)d_in[2];   // [64, 16, 16] fp32
    float* out = (float*)d_out;

    half4* pw = (half4*)d_ws;                 // 64 steps * 64 lanes * 8B = 32KB
    half4* pv = pw + NSTEPS * 64;             // +32KB
    unsigned* lut = (unsigned*)(pv + NSTEPS * 64); // +1KB (ws_size >= 65KB)

    pack_wv<<<16, 256, 0, stream>>>(W, V, pw, pv);
    build_lut256<<<1, 256, 0, stream>>>(lut);

    int batch = in_sizes[0] / DDIM;           // 2^21
    resnet_mfma_kernel<<<batch / 256, 256, 0, stream>>>(x, pw, pv, lut, out);
}